// Round 5
// baseline (169.509 us; speedup 1.0000x reference)
//
#include <hip/hip_runtime.h>
#include <hip/hip_bf16.h>
#include <hip/hip_cooperative_groups.h>

namespace cg = cooperative_groups;

#define N_TOK 65536
#define DIM 64
#define K_CODES 1024

typedef short short8 __attribute__((ext_vector_type(8)));
typedef __bf16 bf16x8 __attribute__((ext_vector_type(8)));
typedef float f32x4 __attribute__((ext_vector_type(4)));
typedef unsigned uintx4 __attribute__((ext_vector_type(4)));

static __device__ __forceinline__ short cvt_bf16(float x) {
    return __builtin_bit_cast(short, __float2bfloat16(x));
}

// Single fused cooperative kernel. 256 blocks x 1024 threads (16 waves), 1 block/CU.
// Wave (rg = w>>2, h = w&3): rows rg*64..+63 vs code tiles h*16..h*16+15.
// LDS B-fragments: frag f = ti*2 + s holds B[k][col] = emb[ti*16 + (lane&15)]
// [s*32 + (lane>>4)*8 + j] at f*512 + lane*8 (shorts). Argmin maximizes
// tv = <l,e>_bf16 + 4 - ||e||^2/2 (> 0) packed with index bits under max_u32.
// Loss = sum_rows(8 - 2*tv_max + ||l||^2), finalized by block 0 after grid.sync.
__global__ __launch_bounds__(1024, 4) void vq_fused(const float* __restrict__ lat,
                                                    const float* __restrict__ emb,
                                                    float* __restrict__ out,
                                                    float* __restrict__ partials) {
    __shared__ __align__(16) short lds_b[65536];      // 128 KB
    __shared__ float lds_cv[K_CODES];                 // 4 KB
    __shared__ __align__(16) unsigned lds_comb[1024]; // [row][h]
    __shared__ int lds_code[256];
    __shared__ float lds_lnp[16];
    __shared__ float lds_rl[4];

    const int tid  = threadIdx.x;
    const int lane = tid & 63;
    const int wave = tid >> 6;
    const int rg = wave >> 2;
    const int h  = wave & 3;
    const int c = lane & 15;
    const int g = lane >> 4;
    const int wrow0 = blockIdx.x * 256 + rg * 64;

    // A-fragments (4 m-tiles of 16 rows) + exact f32 ||l||^2 partial.
    // Issued first so HBM latency hides under the B-stage/convert phase.
    bf16x8 a[4][2];
    float lnp = 0.f;
#pragma unroll
    for (int m = 0; m < 4; ++m) {
        const f32x4* rp4 = reinterpret_cast<const f32x4*>(lat + (size_t)(wrow0 + m * 16 + c) * DIM);
        f32x4 p0 = rp4[g * 2], p1 = rp4[g * 2 + 1];
        f32x4 p2 = rp4[8 + g * 2], p3 = rp4[8 + g * 2 + 1];
        short8 t0, t1;
#pragma unroll
        for (int j = 0; j < 4; ++j) {
            lnp = fmaf(p0[j], p0[j], lnp); lnp = fmaf(p1[j], p1[j], lnp);
            lnp = fmaf(p2[j], p2[j], lnp); lnp = fmaf(p3[j], p3[j], lnp);
            t0[j] = cvt_bf16(p0[j]); t0[4 + j] = cvt_bf16(p1[j]);
            t1[j] = cvt_bf16(p2[j]); t1[4 + j] = cvt_bf16(p3[j]);
        }
        a[m][0] = __builtin_bit_cast(bf16x8, t0);
        a[m][1] = __builtin_bit_cast(bf16x8, t1);
    }
#pragma unroll
    for (int off = 1; off < 64; off <<= 1) lnp += __shfl_xor(lnp, off, 64);
    if (lane == 0) lds_lnp[wave] = lnp;

    // Stage + convert codebook: unit u = (code = u>>3, dims (u&7)*8..+7).
    // Coalesced 32B f32 reads; 8-lane shfl groups reduce code norms in-flight.
#pragma unroll
    for (int i = 0; i < 8; ++i) {
        const int u = i * 1024 + tid;
        const int code = u >> 3, d0 = (u & 7) * 8;
        f32x4 q0 = *reinterpret_cast<const f32x4*>(emb + (size_t)u * 8);
        f32x4 q1 = *reinterpret_cast<const f32x4*>(emb + (size_t)u * 8 + 4);
        float ns = 0.f;
        short8 v;
#pragma unroll
        for (int j = 0; j < 4; ++j) {
            ns = fmaf(q0[j], q0[j], ns); ns = fmaf(q1[j], q1[j], ns);
            v[j] = cvt_bf16(q0[j]); v[4 + j] = cvt_bf16(q1[j]);
        }
        ns += __shfl_xor(ns, 1, 64);
        ns += __shfl_xor(ns, 2, 64);
        ns += __shfl_xor(ns, 4, 64);
        const int f  = (code >> 4) * 2 + (d0 >> 5);
        const int lt = (code & 15) + ((d0 & 31) >> 3) * 16;
        *reinterpret_cast<short8*>(&lds_b[f * 512 + lt * 8]) = v;
        if ((u & 7) == 0) lds_cv[code] = 4.0f - 0.5f * ns;
    }

    unsigned pm[4][4];
#pragma unroll
    for (int m = 0; m < 4; ++m)
#pragma unroll
        for (int j = 0; j < 4; ++j) pm[m][j] = 0u;

    const short* bbase = lds_b + h * 16384 + lane * 8;
    __syncthreads();

#pragma unroll 4
    for (int ti = 0; ti < 16; ++ti) {
        bf16x8 b0 = __builtin_bit_cast(bf16x8,
            *reinterpret_cast<const short8*>(bbase + ti * 1024));
        bf16x8 b1 = __builtin_bit_cast(bf16x8,
            *reinterpret_cast<const short8*>(bbase + ti * 1024 + 512));
        const float cv = lds_cv[(h * 16 + ti) * 16 + c];
        const unsigned ib = 63u - (unsigned)ti;
#pragma unroll
        for (int m = 0; m < 4; ++m) {
            f32x4 acc = {cv, cv, cv, cv};
            acc = __builtin_amdgcn_mfma_f32_16x16x32_bf16(a[m][0], b0, acc, 0, 0, 0);
            acc = __builtin_amdgcn_mfma_f32_16x16x32_bf16(a[m][1], b1, acc, 0, 0, 0);
#pragma unroll
            for (int j = 0; j < 4; ++j) {
                unsigned ub = __builtin_bit_cast(unsigned, acc[j]);
                unsigned pv = (ub & 0xFFFFFFC0u) | ib;
                pm[m][j] = pm[m][j] < pv ? pv : pm[m][j];
            }
        }
    }

    // per-wave reduce over 16 code-columns; repack with 10-bit global code
#pragma unroll
    for (int m = 0; m < 4; ++m) {
#pragma unroll
        for (int j = 0; j < 4; ++j) {
            unsigned v = pm[m][j];
            unsigned gcode = ((unsigned)h * 16u + (63u - (v & 63u))) * 16u + (unsigned)c;
            v = (v & 0xFFFFFC00u) | (1023u - gcode);
#pragma unroll
            for (int off = 1; off < 16; off <<= 1) {
                unsigned o = (unsigned)__shfl_xor((int)v, off, 64);
                v = v < o ? o : v;
            }
            pm[m][j] = v;
        }
    }
    if (c == 0) {
#pragma unroll
        for (int m = 0; m < 4; ++m)
#pragma unroll
            for (int j = 0; j < 4; ++j) {
                const int row = rg * 64 + m * 16 + g * 4 + j;
                lds_comb[row * 4 + h] = pm[m][j];
            }
    }
    __syncthreads();

    // combine across h (256 rows); emit winner code + per-row loss term
    if (tid < 256) {
        uintx4 cm = *reinterpret_cast<const uintx4*>(&lds_comb[tid * 4]);
        unsigned v0 = cm[0] > cm[1] ? cm[0] : cm[1];
        unsigned v1 = cm[2] > cm[3] ? cm[2] : cm[3];
        unsigned v = v0 > v1 ? v0 : v1;
        lds_code[tid] = (int)(1023u - (v & 1023u));
        float tv = __builtin_bit_cast(float, v & 0xFFFFFC00u);
        float rl = fmaf(-2.0f, tv, 8.0f);
#pragma unroll
        for (int off = 1; off < 64; off <<= 1) rl += __shfl_xor(rl, off, 64);
        if (lane == 0) lds_rl[wave] = rl;
    }
    __syncthreads();

    // coalesced output gather: 256 rows x 64 f32 dims as 16B chunks
#pragma unroll
    for (int it = 0; it < 4; ++it) {
        const int cidx = it * 1024 + tid;
        const int row = cidx >> 4, seg = cidx & 15;
        const int gc = lds_code[row];
        reinterpret_cast<f32x4*>(out)[(size_t)(blockIdx.x * 256 + row) * 16 + seg] =
            reinterpret_cast<const f32x4*>(emb)[(size_t)gc * 16 + seg];
    }
    if (tid == 0) {
        partials[blockIdx.x] = lds_rl[0] + lds_rl[1] + lds_rl[2] + lds_rl[3]
                             + lds_lnp[0] + lds_lnp[4] + lds_lnp[8] + lds_lnp[12];
    }

    __threadfence();
    cg::this_grid().sync();

    // block 0 finalizes the loss scalar from the 256 per-block partials
    float p = 0.f;
    if (blockIdx.x == 0 && tid < 256) p = partials[tid];
#pragma unroll
    for (int off = 1; off < 64; off <<= 1) p += __shfl_xor(p, off, 64);
    if (lane == 0) lds_rl[wave & 3] = (wave < 4 && blockIdx.x == 0) ? p : lds_rl[wave & 3];
    __syncthreads();
    if (blockIdx.x == 0 && tid == 0) {
        out[(size_t)N_TOK * DIM] =
            (lds_rl[0] + lds_rl[1] + lds_rl[2] + lds_rl[3]) * (1.25f / 4194304.f);
    }
}

extern "C" void kernel_launch(void* const* d_in, const int* in_sizes, int n_in,
                              void* d_out, int out_size, void* d_ws, size_t ws_size,
                              hipStream_t stream) {
    const float* lat = (const float*)d_in[0];
    const float* emb = (const float*)d_in[1];
    float* out = (float*)d_out;
    float* partials = (float*)d_ws;

    void* args[] = {(void*)&lat, (void*)&emb, (void*)&out, (void*)&partials};
    hipLaunchCooperativeKernel(reinterpret_cast<void*>(vq_fused),
                               dim3(256), dim3(1024), args, 0, stream);
}

// Round 6
// 28.949 us; speedup vs baseline: 5.8554x; 5.8554x over previous
//
#include <hip/hip_runtime.h>
#include <hip/hip_bf16.h>

#define N_TOK 65536
#define DIM 64
#define K_CODES 1024

typedef short short8 __attribute__((ext_vector_type(8)));
typedef __bf16 bf16x8 __attribute__((ext_vector_type(8)));
typedef float f32x4 __attribute__((ext_vector_type(4)));
typedef unsigned uintx4 __attribute__((ext_vector_type(4)));

static __device__ __forceinline__ short cvt_bf16(float x) {
    return __builtin_bit_cast(short, __float2bfloat16(x));
}

// Bank-conflict swizzle for the 128 KB B-tile: permutes 16B chunks within each
// 2 KB window. Applied to BOTH the staging ds_write and the K-loop ds_read.
static __device__ __forceinline__ int swz(int byte_off) {
    return byte_off ^ (((byte_off >> 8) & 7) << 4);
}

// Fused main: 256 blocks x 1024 threads (16 waves, 1 block/CU, 4 waves/SIMD).
// Wave (rg = w>>2, h = w&3): rows rg*64..+63 vs code tiles h*16..+15.
// B-fragments in LDS (swizzled): frag f = ti*2 + s holds B[k][col] =
// emb[ti*16 + (lane&15)][s*32 + (lane>>4)*8 + j] at swz(f*1024 + lane*16) bytes.
// Argmin maximizes tv = <l,e>_bf16 + 4 - ||e||^2/2 (> 0), packed with index
// bits under max_u32. Per-block loss partial -> partials[block] (no atomics).
__global__ __launch_bounds__(1024, 4) void vq_main(const float* __restrict__ lat,
                                                   const float* __restrict__ emb,
                                                   float* __restrict__ out,
                                                   float* __restrict__ partials) {
    __shared__ __align__(16) short lds_b[65536];      // 128 KB
    __shared__ float lds_cv[K_CODES];                 // 4 KB
    __shared__ __align__(16) unsigned lds_comb[1024]; // [row][h]
    __shared__ int lds_code[256];
    __shared__ float lds_lnp[16];
    __shared__ float lds_rl[4];

    const int tid  = threadIdx.x;
    const int lane = tid & 63;
    const int wave = tid >> 6;
    const int rg = wave >> 2;
    const int h  = wave & 3;
    const int c = lane & 15;
    const int g = lane >> 4;
    const int wrow0 = blockIdx.x * 256 + rg * 64;
    char* lds_bc = reinterpret_cast<char*>(lds_b);

    // A-fragments (4 m-tiles of 16 rows) + exact f32 ||l||^2 partial.
    bf16x8 a[4][2];
    float lnp = 0.f;
#pragma unroll
    for (int m = 0; m < 4; ++m) {
        const f32x4* rp4 = reinterpret_cast<const f32x4*>(lat + (size_t)(wrow0 + m * 16 + c) * DIM);
        f32x4 p0 = rp4[g * 2], p1 = rp4[g * 2 + 1];
        f32x4 p2 = rp4[8 + g * 2], p3 = rp4[8 + g * 2 + 1];
        short8 t0, t1;
#pragma unroll
        for (int j = 0; j < 4; ++j) {
            lnp = fmaf(p0[j], p0[j], lnp); lnp = fmaf(p1[j], p1[j], lnp);
            lnp = fmaf(p2[j], p2[j], lnp); lnp = fmaf(p3[j], p3[j], lnp);
            t0[j] = cvt_bf16(p0[j]); t0[4 + j] = cvt_bf16(p1[j]);
            t1[j] = cvt_bf16(p2[j]); t1[4 + j] = cvt_bf16(p3[j]);
        }
        a[m][0] = __builtin_bit_cast(bf16x8, t0);
        a[m][1] = __builtin_bit_cast(bf16x8, t1);
    }
#pragma unroll
    for (int off = 1; off < 64; off <<= 1) lnp += __shfl_xor(lnp, off, 64);
    if (lane == 0) lds_lnp[wave] = lnp;

    // Stage + convert codebook: unit u = (code = u>>3, dims (u&7)*8..+7).
    // Coalesced 32B f32 reads; 8-lane shfl groups reduce code norms in-flight.
#pragma unroll
    for (int i = 0; i < 8; ++i) {
        const int u = i * 1024 + tid;
        const int code = u >> 3, d0 = (u & 7) * 8;
        f32x4 q0 = *reinterpret_cast<const f32x4*>(emb + (size_t)u * 8);
        f32x4 q1 = *reinterpret_cast<const f32x4*>(emb + (size_t)u * 8 + 4);
        float ns = 0.f;
        short8 v;
#pragma unroll
        for (int j = 0; j < 4; ++j) {
            ns = fmaf(q0[j], q0[j], ns); ns = fmaf(q1[j], q1[j], ns);
            v[j] = cvt_bf16(q0[j]); v[4 + j] = cvt_bf16(q1[j]);
        }
        ns += __shfl_xor(ns, 1, 64);
        ns += __shfl_xor(ns, 2, 64);
        ns += __shfl_xor(ns, 4, 64);
        const int f  = (code >> 4) * 2 + (d0 >> 5);
        const int lt = (code & 15) + ((d0 & 31) >> 3) * 16;
        *reinterpret_cast<short8*>(lds_bc + swz(f * 1024 + lt * 16)) = v;
        if ((u & 7) == 0) lds_cv[code] = 4.0f - 0.5f * ns;
    }

    unsigned pm[4][4];
#pragma unroll
    for (int m = 0; m < 4; ++m)
#pragma unroll
        for (int j = 0; j < 4; ++j) pm[m][j] = 0u;

    const int bbyte = h * 32768 + lane * 16;   // base byte of this wave's B reads
    __syncthreads();

#pragma unroll 4
    for (int ti = 0; ti < 16; ++ti) {
        bf16x8 b0 = __builtin_bit_cast(bf16x8,
            *reinterpret_cast<const short8*>(lds_bc + swz(bbyte + ti * 2048)));
        bf16x8 b1 = __builtin_bit_cast(bf16x8,
            *reinterpret_cast<const short8*>(lds_bc + swz(bbyte + ti * 2048 + 1024)));
        const float cv = lds_cv[(h * 16 + ti) * 16 + c];
        const unsigned ib = 63u - (unsigned)ti;
#pragma unroll
        for (int m = 0; m < 4; ++m) {
            f32x4 acc = {cv, cv, cv, cv};
            acc = __builtin_amdgcn_mfma_f32_16x16x32_bf16(a[m][0], b0, acc, 0, 0, 0);
            acc = __builtin_amdgcn_mfma_f32_16x16x32_bf16(a[m][1], b1, acc, 0, 0, 0);
#pragma unroll
            for (int j = 0; j < 4; ++j) {
                unsigned ub = __builtin_bit_cast(unsigned, acc[j]);
                unsigned pv = (ub & 0xFFFFFFC0u) | ib;
                pm[m][j] = pm[m][j] < pv ? pv : pm[m][j];
            }
        }
    }

    // per-wave reduce over 16 code-columns; repack with 10-bit global code
#pragma unroll
    for (int m = 0; m < 4; ++m) {
#pragma unroll
        for (int j = 0; j < 4; ++j) {
            unsigned v = pm[m][j];
            unsigned gcode = ((unsigned)h * 16u + (63u - (v & 63u))) * 16u + (unsigned)c;
            v = (v & 0xFFFFFC00u) | (1023u - gcode);
#pragma unroll
            for (int off = 1; off < 16; off <<= 1) {
                unsigned o = (unsigned)__shfl_xor((int)v, off, 64);
                v = v < o ? o : v;
            }
            pm[m][j] = v;
        }
    }
    if (c == 0) {
#pragma unroll
        for (int m = 0; m < 4; ++m)
#pragma unroll
            for (int j = 0; j < 4; ++j) {
                const int row = rg * 64 + m * 16 + g * 4 + j;
                lds_comb[row * 4 + h] = pm[m][j];
            }
    }
    __syncthreads();

    // combine across h (256 rows); emit winner code + per-row loss term
    if (tid < 256) {
        uintx4 cm = *reinterpret_cast<const uintx4*>(&lds_comb[tid * 4]);
        unsigned v0 = cm[0] > cm[1] ? cm[0] : cm[1];
        unsigned v1 = cm[2] > cm[3] ? cm[2] : cm[3];
        unsigned v = v0 > v1 ? v0 : v1;
        lds_code[tid] = (int)(1023u - (v & 1023u));
        float tv = __builtin_bit_cast(float, v & 0xFFFFFC00u);
        float rl = fmaf(-2.0f, tv, 8.0f);
#pragma unroll
        for (int off = 1; off < 64; off <<= 1) rl += __shfl_xor(rl, off, 64);
        if (lane == 0) lds_rl[wave] = rl;
    }
    __syncthreads();

    // coalesced output gather: 256 rows x 64 f32 dims as 16B chunks
#pragma unroll
    for (int it = 0; it < 4; ++it) {
        const int cidx = it * 1024 + tid;
        const int row = cidx >> 4, seg = cidx & 15;
        const int gc = lds_code[row];
        reinterpret_cast<f32x4*>(out)[(size_t)(blockIdx.x * 256 + row) * 16 + seg] =
            reinterpret_cast<const f32x4*>(emb)[(size_t)gc * 16 + seg];
    }
    if (tid == 0) {
        partials[blockIdx.x] = lds_rl[0] + lds_rl[1] + lds_rl[2] + lds_rl[3]
                             + lds_lnp[0] + lds_lnp[4] + lds_lnp[8] + lds_lnp[12];
    }
}

// one wave: sum 256 per-block partials, scale, write loss scalar
__global__ __launch_bounds__(64) void vq_finalize(const float* __restrict__ partials,
                                                  float* __restrict__ loss_out) {
    const int lane = threadIdx.x;
    f32x4 p4 = reinterpret_cast<const f32x4*>(partials)[lane];
    float p = (p4[0] + p4[1]) + (p4[2] + p4[3]);
#pragma unroll
    for (int off = 1; off < 64; off <<= 1) p += __shfl_xor(p, off, 64);
    if (lane == 0) loss_out[0] = p * (1.25f / 4194304.f);
}

extern "C" void kernel_launch(void* const* d_in, const int* in_sizes, int n_in,
                              void* d_out, int out_size, void* d_ws, size_t ws_size,
                              hipStream_t stream) {
    const float* lat = (const float*)d_in[0];
    const float* emb = (const float*)d_in[1];
    float* out = (float*)d_out;
    float* partials = (float*)d_ws;

    vq_main<<<256, 1024, 0, stream>>>(lat, emb, out, partials);
    vq_finalize<<<1, 64, 0, stream>>>(partials, out + (size_t)N_TOK * DIM);
}